// Round 4
// baseline (877.664 us; speedup 1.0000x reference)
//
#include <hip/hip_runtime.h>

// MPNN: N=50000, E=800000, DIN=64, EIN=32, EOUT=64, H=128, DOUT=64
// Inputs f32 (confirmed: bf16 misread gave NaN, f32 read gives finite).
// This round probes OUTPUT dtype = f32 (reference's dtype per harness doc).
// ws shrunk to 6.95 MB: f32 agg lives in d_out's uh_n region (written by agg_kernel,
// read into LDS by node_kernel before overwriting the same rows - block-local, safe).

typedef unsigned short u16;
typedef __attribute__((ext_vector_type(8))) short bf16x8;
typedef __attribute__((ext_vector_type(4))) float f32x4;

#define NN 50000
#define NE 800000

__device__ __forceinline__ u16 f2bf(float f){
  union { float f; unsigned int i; } v; v.f = f;
  unsigned int i = v.i;
  return (u16)((i + 0x7FFFu + ((i >> 16) & 1u)) >> 16);  // RNE
}
__device__ __forceinline__ uint2 f4tobf(float4 f){
  uint2 p;
  p.x = (unsigned)f2bf(f.x) | ((unsigned)f2bf(f.y) << 16);
  p.y = (unsigned)f2bf(f.z) | ((unsigned)f2bf(f.w) << 16);
  return p;
}

// ---------------- prep: f32 weights -> transposed bf16 [n][k]; head = -1 ----------------
__global__ void prep_kernel(const float* __restrict__ We1, const float* __restrict__ Wa1,
                            const float* __restrict__ We2, const float* __restrict__ Wa2,
                            const float* __restrict__ Wn1, const float* __restrict__ Wn2,
                            u16* __restrict__ w1t, u16* __restrict__ w2t,
                            u16* __restrict__ wn1t, u16* __restrict__ wn2t,
                            int* __restrict__ head)
{
  int i = blockIdx.x * 256 + threadIdx.x;
  if (i < 40960) {
    int n = i / 160, k = i % 160;
    w1t[i] = f2bf((n < 128) ? We1[k*128 + n] : Wa1[k*128 + (n-128)]);
  } else if (i < 51200) {
    int j = i - 40960; int n = j / 128, k = j % 128;
    float v = (n < 64) ? We2[k*64 + n] : ((n == 64) ? Wa2[k] : 0.f);
    w2t[j] = f2bf(v);
  } else if (i < 67584) {
    int j = i - 51200; int n = j / 128, k = j % 128;
    wn1t[j] = f2bf(Wn1[k*128 + n]);
  } else if (i < 75776) {
    int j = i - 67584; int n = j / 128, k = j % 128;
    wn2t[j] = f2bf(Wn2[k*64 + n]);
  } else if (i < 125776) {
    head[i - 75776] = -1;
  }
}

// ---------------- linked-list build over dst ----------------
__global__ void link_kernel(const int* __restrict__ dst, int* __restrict__ head,
                            int* __restrict__ nxt)
{
  int e = blockIdx.x * 256 + threadIdx.x;
  if (e >= NE) return;
  nxt[e] = atomicExch(&head[dst[e]], e);
}

// ---------------- edge MLP + attn logit (fused, MFMA) ----------------
__global__ __launch_bounds__(256, 2) void edge_kernel(
    const float* __restrict__ nf, const float* __restrict__ ef,
    const int* __restrict__ src, const int* __restrict__ dst,
    const u16* __restrict__ w1t, const u16* __restrict__ w2t,
    const float* __restrict__ be1, const float* __restrict__ ba1,
    const float* __restrict__ be2, const float* __restrict__ ba2,
    float* __restrict__ uh_e, float* __restrict__ logits)
{
  __shared__ u16 eins[64*168];       // e_in tile [64][160] bf16, pad->168
  __shared__ u16 hsm[4][16*264];     // per-wave hidden [16][256] pad->264
  __shared__ float outs[64*64];      // uh_e staging (f32)
  __shared__ int s_src[64], s_dst[64];

  const int t = threadIdx.x;
  const int base = blockIdx.x * 64;

  if (t < 64)        s_src[t]      = src[base + t];
  else if (t < 128)  s_dst[t - 64] = dst[base + (t - 64)];
  __syncthreads();

  // gather + f32->bf16: nf[src] (cols 0..63), nf[dst] (64..127), ef (128..159)
  #pragma unroll
  for (int i = 0; i < 4; i++) {
    int idx = i*256 + t;
    int e = idx >> 4, c = idx & 15;
    float4 f = *(const float4*)(nf + (size_t)s_src[e]*64 + c*4);
    *(uint2*)&eins[e*168 + c*4] = f4tobf(f);
  }
  #pragma unroll
  for (int i = 0; i < 4; i++) {
    int idx = i*256 + t;
    int e = idx >> 4, c = idx & 15;
    float4 f = *(const float4*)(nf + (size_t)s_dst[e]*64 + c*4);
    *(uint2*)&eins[e*168 + 64 + c*4] = f4tobf(f);
  }
  #pragma unroll
  for (int i = 0; i < 2; i++) {
    int idx = i*256 + t;
    int e = idx >> 3, c = idx & 7;
    float4 f = *(const float4*)(ef + (size_t)(base + e)*32 + c*4);
    *(uint2*)&eins[e*168 + 128 + c*4] = f4tobf(f);
  }
  __syncthreads();

  const int lane = t & 63, wave = t >> 6;
  const int r = lane & 15, quad = lane >> 4;

  // ---- layer 1: [64x160] @ [160x256] (We1|Wa1 fused) ----
  f32x4 acc[16];
  #pragma unroll
  for (int i = 0; i < 16; i++) acc[i] = {0.f, 0.f, 0.f, 0.f};

  const u16* arow = &eins[(wave*16 + r)*168 + quad*8];
  #pragma unroll
  for (int k0 = 0; k0 < 160; k0 += 32) {
    bf16x8 a = *(const bf16x8*)(arow + k0);
    #pragma unroll
    for (int tt = 0; tt < 16; tt++) {
      bf16x8 b = *(const bf16x8*)(w1t + (size_t)(tt*16 + r)*160 + k0 + quad*8);
      acc[tt] = __builtin_amdgcn_mfma_f32_16x16x32_bf16(a, b, acc[tt], 0, 0, 0);
    }
  }

  // bias + relu, C-layout (col=lane&15, row=quad*4+i) -> LDS row-major
  u16* hb = &hsm[wave][0];
  #pragma unroll
  for (int tt = 0; tt < 16; tt++) {
    int col = tt*16 + r;
    float bias = (col < 128) ? be1[col] : ba1[col - 128];
    #pragma unroll
    for (int i = 0; i < 4; i++) {
      float h = fmaxf(acc[tt][i] + bias, 0.f);
      hb[(quad*4 + i)*264 + col] = f2bf(h);
    }
  }
  __syncthreads();

  // ---- layer 2: uh_e = h_e[16x128] @ We2[128x64]; logit = h_a @ Wa2 ----
  f32x4 acc2[5];
  #pragma unroll
  for (int i = 0; i < 5; i++) acc2[i] = {0.f, 0.f, 0.f, 0.f};
  #pragma unroll
  for (int k0 = 0; k0 < 128; k0 += 32) {
    bf16x8 ae = *(const bf16x8*)&hb[r*264 + k0 + quad*8];
    bf16x8 aa = *(const bf16x8*)&hb[r*264 + 128 + k0 + quad*8];
    #pragma unroll
    for (int tt = 0; tt < 4; tt++) {
      bf16x8 b = *(const bf16x8*)(w2t + (size_t)(tt*16 + r)*128 + k0 + quad*8);
      acc2[tt] = __builtin_amdgcn_mfma_f32_16x16x32_bf16(ae, b, acc2[tt], 0, 0, 0);
    }
    bf16x8 b4 = *(const bf16x8*)(w2t + (size_t)(64 + r)*128 + k0 + quad*8);
    acc2[4] = __builtin_amdgcn_mfma_f32_16x16x32_bf16(aa, b4, acc2[4], 0, 0, 0);
  }

  // epilogue: uh_e (f32) -> LDS staging; logit -> global f32
  #pragma unroll
  for (int tt = 0; tt < 4; tt++) {
    int col = tt*16 + r;
    float bias = be2[col];
    #pragma unroll
    for (int i = 0; i < 4; i++)
      outs[(wave*16 + quad*4 + i)*64 + col] = acc2[tt][i] + bias;
  }
  if (r == 0) {
    float bias = ba2[0];
    #pragma unroll
    for (int i = 0; i < 4; i++)
      logits[base + wave*16 + quad*4 + i] = acc2[4][i] + bias;
  }
  __syncthreads();

  // coalesced f32 uh_e store: 64 rows x 16 float4
  #pragma unroll
  for (int i = 0; i < 4; i++) {
    int idx = i*256 + t;
    int row = idx >> 4, c = idx & 15;
    *(float4*)(uh_e + (size_t)(base + row)*64 + c*4) = *(const float4*)&outs[row*64 + c*4];
  }
}

// ---------------- segment softmax (thread per node, chain walk) ----------------
__global__ void soft_kernel(const int* __restrict__ head, const int* __restrict__ nxt,
                            float* __restrict__ logits, float* __restrict__ invden)
{
  int v = blockIdx.x * 256 + threadIdx.x;
  if (v >= NN) return;
  int e = head[v];
  float m = -3.0e38f;
  while (e >= 0) { m = fmaxf(m, logits[e]); e = nxt[e]; }
  float s = 0.f;
  e = head[v];
  while (e >= 0) { float x = __expf(logits[e] - m); logits[e] = x; s += x; e = nxt[e]; }
  invden[v] = 1.f / fmaxf(s, 1e-38f);
}

// ---------------- attention-weighted aggregation (wave per node) ----------------
// writes f32 agg into d_out's uh_n region (node_kernel stages it before overwriting)
__global__ void agg_kernel(const int* __restrict__ head, const int* __restrict__ nxt,
                           const float* __restrict__ attn_u, const float* __restrict__ invden,
                           const float* __restrict__ uh_e, float* __restrict__ aggf)
{
  int gid = blockIdx.x * 256 + threadIdx.x;
  int v = gid >> 6, lane = gid & 63;
  if (v >= NN) return;
  float inv = invden[v];
  float acc = 0.f;
  int e = head[v];
  while (e >= 0) {
    acc += (attn_u[e] * inv) * uh_e[(size_t)e*64 + lane];
    e = nxt[e];
  }
  aggf[(size_t)v*64 + lane] = acc;
}

// ---------------- node MLP (MFMA); reads agg from uh_n region, overwrites with uh_n ----
__global__ __launch_bounds__(256, 2) void node_kernel(
    const float* __restrict__ aggf, const float* __restrict__ nf,
    const u16* __restrict__ wn1t, const u16* __restrict__ wn2t,
    const float* __restrict__ bn1, const float* __restrict__ bn2,
    float* __restrict__ uh_n)
{
  __shared__ u16 xs[64*136];        // x tile [64][128] bf16, pad->136
  __shared__ u16 hsm[4][16*136];
  __shared__ float outs[64*64];

  const int t = threadIdx.x;
  const int base = blockIdx.x * 64;

  // xs: cols 0..63 = aggf (f32->bf16), cols 64..127 = nf (f32->bf16); 32 float4/row
  #pragma unroll
  for (int i = 0; i < 8; i++) {
    int idx = i*256 + t;            // 0..2047
    int row = idx >> 5, c = idx & 31;
    int v = base + row;
    float4 f = {0.f, 0.f, 0.f, 0.f};
    if (v < NN) {
      if (c < 16) f = *(const float4*)(aggf + (size_t)v*64 + c*4);
      else        f = *(const float4*)(nf   + (size_t)v*64 + (c-16)*4);
    }
    *(uint2*)&xs[row*136 + c*4] = f4tobf(f);
  }
  __syncthreads();

  const int lane = t & 63, wave = t >> 6;
  const int r = lane & 15, quad = lane >> 4;

  f32x4 acc1[8];
  #pragma unroll
  for (int i = 0; i < 8; i++) acc1[i] = {0.f, 0.f, 0.f, 0.f};
  #pragma unroll
  for (int k0 = 0; k0 < 128; k0 += 32) {
    bf16x8 a = *(const bf16x8*)&xs[(wave*16 + r)*136 + k0 + quad*8];
    #pragma unroll
    for (int tt = 0; tt < 8; tt++) {
      bf16x8 b = *(const bf16x8*)(wn1t + (size_t)(tt*16 + r)*128 + k0 + quad*8);
      acc1[tt] = __builtin_amdgcn_mfma_f32_16x16x32_bf16(a, b, acc1[tt], 0, 0, 0);
    }
  }

  u16* hb = &hsm[wave][0];
  #pragma unroll
  for (int tt = 0; tt < 8; tt++) {
    int col = tt*16 + r;
    float bias = bn1[col];
    #pragma unroll
    for (int i = 0; i < 4; i++) {
      float h = fmaxf(acc1[tt][i] + bias, 0.f);
      hb[(quad*4 + i)*136 + col] = f2bf(h);
    }
  }
  __syncthreads();

  f32x4 acc2[4];
  #pragma unroll
  for (int i = 0; i < 4; i++) acc2[i] = {0.f, 0.f, 0.f, 0.f};
  #pragma unroll
  for (int k0 = 0; k0 < 128; k0 += 32) {
    bf16x8 a = *(const bf16x8*)&hb[r*136 + k0 + quad*8];
    #pragma unroll
    for (int tt = 0; tt < 4; tt++) {
      bf16x8 b = *(const bf16x8*)(wn2t + (size_t)(tt*16 + r)*128 + k0 + quad*8);
      acc2[tt] = __builtin_amdgcn_mfma_f32_16x16x32_bf16(a, b, acc2[tt], 0, 0, 0);
    }
  }

  #pragma unroll
  for (int tt = 0; tt < 4; tt++) {
    int col = tt*16 + r;
    float bias = bn2[col];
    #pragma unroll
    for (int i = 0; i < 4; i++)
      outs[(wave*16 + quad*4 + i)*64 + col] = acc2[tt][i] + bias;
  }
  __syncthreads();

  #pragma unroll
  for (int i = 0; i < 4; i++) {
    int idx = i*256 + t;
    int row = idx >> 4, c = idx & 15;
    int v2 = base + row;
    if (v2 < NN)
      *(float4*)(uh_n + (size_t)v2*64 + c*4) = *(const float4*)&outs[row*64 + c*4];
  }
}

// ---------------- launch ----------------
extern "C" void kernel_launch(void* const* d_in, const int* in_sizes, int n_in,
                              void* d_out, int out_size, void* d_ws, size_t ws_size,
                              hipStream_t stream)
{
  const float* nf  = (const float*)d_in[0];
  const float* ef  = (const float*)d_in[1];
  const int*   src = (const int*)d_in[2];
  const int*   dst = (const int*)d_in[3];
  const float* We1 = (const float*)d_in[4];
  const float* be1 = (const float*)d_in[5];
  const float* We2 = (const float*)d_in[6];
  const float* be2 = (const float*)d_in[7];
  const float* Wa1 = (const float*)d_in[8];
  const float* ba1 = (const float*)d_in[9];
  const float* Wa2 = (const float*)d_in[10];
  const float* ba2 = (const float*)d_in[11];
  const float* Wn1 = (const float*)d_in[12];
  const float* bn1 = (const float*)d_in[13];
  const float* Wn2 = (const float*)d_in[14];
  const float* bn2 = (const float*)d_in[15];

  // workspace layout (bytes), total 6,951,552 B (~6.6 MiB)
  char* ws = (char*)d_ws;
  u16*   w1t    = (u16*)  (ws + 0);         //  81920 B
  u16*   w2t    = (u16*)  (ws + 81920);     //  20480 B
  u16*   wn1t   = (u16*)  (ws + 102400);    //  32768 B
  u16*   wn2t   = (u16*)  (ws + 135168);    //  16384 B
  float* logits = (float*)(ws + 151552);    //  NE*4 (becomes attn in-place)
  float* invden = (float*)(ws + 3351552);   //  NN*4
  int*   head   = (int*)  (ws + 3551552);   //  NN*4
  int*   nxt    = (int*)  (ws + 3751552);   //  NE*4  -> end 6,951,552

  float* uh_n = (float*)d_out;                     // [NN, 64] f32 (agg staged here first)
  float* uh_e = (float*)d_out + (size_t)NN * 64;   // [NE, 64] f32

  prep_kernel<<<492, 256, 0, stream>>>(We1, Wa1, We2, Wa2, Wn1, Wn2,
                                       w1t, w2t, wn1t, wn2t, head);
  link_kernel<<<(NE + 255)/256, 256, 0, stream>>>(dst, head, nxt);
  edge_kernel<<<NE/64, 256, 0, stream>>>(nf, ef, src, dst, w1t, w2t,
                                         be1, ba1, be2, ba2, uh_e, logits);
  soft_kernel<<<(NN + 255)/256, 256, 0, stream>>>(head, nxt, logits, invden);
  agg_kernel<<<(NN*64)/256, 256, 0, stream>>>(head, nxt, logits, invden, uh_e, uh_n);
  node_kernel<<<(NN + 63)/64, 256, 0, stream>>>(uh_n, nf, wn1t, wn2t, bn1, bn2, uh_n);
}